// Round 10
// baseline (590.688 us; speedup 1.0000x reference)
//
#include <hip/hip_runtime.h>
#include <hip/hip_bf16.h>

#define DIV_UP(a,b) (((a)+(b)-1)/(b))

typedef __attribute__((ext_vector_type(8))) short bfrag;    // 8 bf16 = 4 VGPR
typedef __attribute__((ext_vector_type(4))) float accf;     // 16x16 MFMA acc
typedef __attribute__((ext_vector_type(16))) float accf16;  // 32x32 MFMA acc

__device__ __forceinline__ unsigned short f2bf(float f) {
    __hip_bfloat16 h = __float2bfloat16(f);
    return *reinterpret_cast<unsigned short*>(&h);
}

// ---------------------------------------------------------------------------
// conv1 + pool1 via MFMA im2col: x[256,3,32,32] f32 -> CA[chunk,64,16,16] bf16.
// ---------------------------------------------------------------------------
__global__ __launch_bounds__(256) void conv1_mfma(
    const float* __restrict__ in, const float* __restrict__ w,
    const float* __restrict__ bias, unsigned short* __restrict__ out, int n0)
{
    constexpr int RAWS = 3 * 6 * 34;            // 612 shorts ([3][6][34] bf16)
    constexpr int INS  = 128 * 32;              // im2col [128 pos][32 k]
    constexpr int WSZ  = 64 * 32;               // [64 oc][32 k]
    constexpr int CS   = 128 * 66;              // floats
    constexpr int SMEM = (CS * 4 > (RAWS + 4 + INS + WSZ) * 2)
                       ? CS * 4 : (RAWS + 4 + INS + WSZ) * 2;
    __shared__ __align__(16) char smem[SMEM];
    short* raw_s = (short*)smem;
    short* in_s  = raw_s + RAWS + 4;
    short* w_s   = in_s + INS;
    float* c_s   = (float*)smem;

    const int tid  = threadIdx.x;
    const int lane = tid & 63, wv = tid >> 6;
    const int quad = lane >> 4, lr = lane & 15;
    const int rb   = blockIdx.x;
    const int nl   = blockIdx.y;
    const int n    = n0 + nl;
    const int row0 = rb * 4;

    for (int idx = tid; idx < RAWS; idx += 256) {
        int c = idx / 204, rem = idx - c * 204;
        int ry = rem / 34, rx = rem - ry * 34;
        int iy = row0 - 1 + ry, ix = rx - 1;
        float v = 0.f;
        if (iy >= 0 && iy < 32 && ix >= 0 && ix < 32)
            v = in[((n * 3 + c) * 32 + iy) * 32 + ix];
        raw_s[idx] = (short)f2bf(v);
    }
    {
        const int soc = tid >> 2, cbq = tid & 3;
        const int wsw = ((cbq ^ ((soc >> 1) & 3)) << 3);
        __align__(16) unsigned short buf[8];
#pragma unroll
        for (int j = 0; j < 8; ++j) {
            int k = cbq * 8 + j;
            buf[j] = (k < 27) ? f2bf(w[soc * 27 + k]) : (unsigned short)0;
        }
        *(uint4*)&w_s[soc * 32 + wsw] = *(uint4*)buf;
    }
    __syncthreads();
    {
        const int k = tid & 31, pg = tid >> 5;
        const int shi = k >> 3, slo = k & 7;
        const bool valid = (k < 27);
        int cbase = 0;
        if (valid) {
            int c = k / 9, rr = k - c * 9;
            int ky = rr / 3, kx = rr - ky * 3;
            cbase = c * 204 + ky * 34 + kx;
        }
        const int prow = pg >> 1, pcol0 = (pg & 1) * 16;
        const int rbase = cbase + prow * 34 + pcol0;
#pragma unroll
        for (int i = 0; i < 16; ++i) {
            const int pos = prow * 32 + pcol0 + i;
            short v = valid ? raw_s[rbase + i] : (short)0;
            in_s[pos * 32 + ((shi ^ ((pos >> 1) & 3)) << 3) + slo] = v;
        }
    }
    __syncthreads();
    const int bswz = (quad ^ ((lr >> 1) & 3)) << 3;
    const bfrag b = *(const bfrag*)(w_s + (wv * 16 + lr) * 32 + bswz);
    accf acc[8];
#pragma unroll
    for (int mt = 0; mt < 8; ++mt) {
        const int pos = mt * 16 + lr;
        const bfrag a = *(const bfrag*)(in_s + pos * 32 + ((quad ^ ((pos >> 1) & 3)) << 3));
        acc[mt] = __builtin_amdgcn_mfma_f32_16x16x32_bf16(
            a, b, (accf){0.f, 0.f, 0.f, 0.f}, 0, 0, 0);
    }
    __syncthreads();
#pragma unroll
    for (int mt = 0; mt < 8; ++mt)
#pragma unroll
        for (int r = 0; r < 4; ++r)
            c_s[(mt * 16 + quad * 4 + r) * 66 + wv * 16 + lr] = acc[mt][r];
    __syncthreads();
    {
        const int oc = tid >> 2;
        const float bv = bias[oc];
        const int o0 = (tid & 3) * 8;
        __align__(16) unsigned short buf[8];
#pragma unroll
        for (int i = 0; i < 8; ++i) {
            int op = o0 + i, oy = op >> 4, ox = op & 15;
            int p = (oy * 2) * 32 + ox * 2;
            float v = fmaxf(fmaxf(c_s[p * 66 + oc],        c_s[(p + 1) * 66 + oc]),
                            fmaxf(c_s[(p + 32) * 66 + oc], c_s[(p + 33) * 66 + oc]));
            buf[i] = f2bf(fmaxf(v + bv, 0.f));
        }
        unsigned short* dst = out + ((size_t)(nl * 64 + oc)) * 256 + (row0 >> 1) * 16 + o0;
        *(uint4*)dst = *(uint4*)buf;
    }
}

// ---------------------------------------------------------------------------
// Weight pre-transform (once per launch): f32 OIHW -> bf16, emitted as
// CONTIGUOUS 32x32x16 B-fragments so conv_mfma32 loads B straight from
// global (L2-resident), fully coalesced (1KB per wave-load), no LDS:
//   wt[ ((g*NC + cc)*NOCG + ocg)*1024 + kh*512 + lane*8 + j ]
//     = w[oc = ocg*32 + (lane&31)][ci = cc*32 + kh*16 + (lane>>5)*8 + j][g]
// ---------------------------------------------------------------------------
__global__ __launch_bounds__(256) void wt_transform(
    const float* __restrict__ w, unsigned short* __restrict__ wt,
    int COUT, int CIN, int KK, int total)
{
    int idx = blockIdx.x * 256 + threadIdx.x;
    if (idx >= total) return;
    const int j    = idx & 7;
    const int lane = (idx >> 3) & 63;
    const int kh   = (idx >> 9) & 1;
    int t = idx >> 10;
    const int NOCG = COUT >> 5;
    const int ocg  = t % NOCG; t /= NOCG;
    const int NC   = CIN >> 5;
    const int cc   = t % NC;
    const int g    = t / NC;
    const int oc = ocg * 32 + (lane & 31);
    const int ci = cc * 32 + kh * 16 + (lane >> 5) * 8 + j;
    wt[idx] = f2bf(w[((size_t)oc * CIN + ci) * KK + g]);
}

// ---------------------------------------------------------------------------
// 32x32x16-MFMA implicit-GEMM conv (unchanged from r8, oc0 fix included).
// ---------------------------------------------------------------------------
template<int CIN, int KS, int HIN, int IMGS, int MODE, int COUT>
__global__ __launch_bounds__(256) void conv_mfma32(
    const unsigned short* __restrict__ in, const unsigned short* __restrict__ wt,
    const float* __restrict__ bias, unsigned short* __restrict__ out)
{
    constexpr int PAD  = KS / 2;
    constexpr int KK   = KS * KS;
    constexpr int PIX  = HIN * HIN;
    constexpr int NC   = CIN / 32;
    constexpr int NOCG = COUT / 32;
    constexpr int IPOS = IMGS * PIX;               // staged positions
    constexpr int ROWB = (IMGS == 1) ? PIX / 128 : 1;
    constexpr int INS  = IPOS * 32 + 32;           // shorts (incl zero row)
    constexpr int CS   = 128 * 66;                 // floats
    constexpr int SMEM = (INS * 2 > CS * 4) ? INS * 2 : CS * 4;
    constexpr int GSTR = NC * NOCG * 1024;         // wt shorts per tap g

    __shared__ __align__(16) char smem[SMEM];
    short* in_s = (short*)smem;
    float* c_s  = (float*)smem;

    const int tid  = threadIdx.x;
    const int lane = tid & 63, wv = tid >> 6;
    const int hi   = lane >> 5, lr32 = lane & 31;
    const int wvM  = wv >> 1, wvN = wv & 1;
    const int ocb  = blockIdx.x / ROWB, rb = blockIdx.x % ROWB;
    const int oc0  = ocb * 64;
    const int nl0  = (IMGS == 2) ? blockIdx.y * 2 : blockIdx.y;
    const int row0 = rb * (128 / HIN);             // conv2 band start row

    if (tid < 32) in_s[IPOS * 32 + tid] = 0;       // zero row for OOB taps

    accf16 acc[2];
#pragma unroll
    for (int i = 0; i < 2; ++i)
#pragma unroll
        for (int r = 0; r < 16; ++r) acc[i][r] = 0.f;

    // Hoisted A addressing (KS==3); conv2 computes inline.
    int pym[2], pxm[2];
#pragma unroll
    for (int mt = 0; mt < 2; ++mt) {
        const int m = wvM * 64 + mt * 32 + lr32;
        pym[mt] = row0 + m / HIN;
        pxm[mt] = m % HIN;
    }
    int apos[KK][2];
    if constexpr (KS == 3) {
#pragma unroll
        for (int g = 0; g < KK; ++g) {
            const int dy = g / 3 - 1, dx = g % 3 - 1;
#pragma unroll
            for (int mt = 0; mt < 2; ++mt) {
                const int m = wvM * 64 + mt * 32 + lr32;
                const int img = m >> 6, p = m & 63;
                const int iy = (p >> 3) + dy, ix = (p & 7) + dx;
                const bool ok = ((unsigned)iy < 8u) & ((unsigned)ix < 8u);
                const int pos = ok ? img * 64 + iy * 8 + ix : IPOS;
                apos[g][mt] = pos * 64 + ((hi ^ ((pos >> 1) & 3)) << 4);
            }
        }
    }

    const int sci = tid & 31, slot = tid >> 5;
    const int shi = sci >> 3, slo = sci & 7;
    // B fragment base: this wave's oc-group, lane-contiguous layout.
    const unsigned short* wbase = wt + (size_t)(oc0 / 32 + wvN) * 1024 + lane * 8;

    for (int c0 = 0; c0 < CIN; c0 += 32) {
        const unsigned short* wb = wbase + (size_t)(c0 >> 5) * (NOCG * 1024);
        __syncthreads();
        // stage input images -> in_s[pos][ci] (swizzled 16B slots)
#pragma unroll
        for (int img = 0; img < IMGS; ++img) {
            const unsigned short* src = in + ((size_t)((nl0 + img) * CIN + c0 + sci)) * PIX;
            for (int iy = slot; iy < HIN; iy += 8) {
#pragma unroll
                for (int xc = 0; xc < HIN; xc += 8) {
                    uint4 v = *(const uint4*)(src + iy * HIN + xc);
                    const int p0 = img * PIX + iy * HIN + xc;
                    unsigned short e[8];
                    e[0] = (unsigned short)(v.x & 0xFFFF); e[1] = (unsigned short)(v.x >> 16);
                    e[2] = (unsigned short)(v.y & 0xFFFF); e[3] = (unsigned short)(v.y >> 16);
                    e[4] = (unsigned short)(v.z & 0xFFFF); e[5] = (unsigned short)(v.z >> 16);
                    e[6] = (unsigned short)(v.w & 0xFFFF); e[7] = (unsigned short)(v.w >> 16);
#pragma unroll
                    for (int k = 0; k < 8; ++k) {
                        const int p = p0 + k;
                        in_s[p * 32 + ((shi ^ ((p >> 1) & 3)) << 3) + slo] = (short)e[k];
                    }
                }
            }
        }
        // issue first B loads while staging drains
        bfrag bc0 = *(const bfrag*)(wb);
        bfrag bc1 = *(const bfrag*)(wb + 512);
        __syncthreads();
#pragma unroll
        for (int g = 0; g < KK; ++g) {
            bfrag bn0 = bc0, bn1 = bc1;
            if (g + 1 < KK) {                      // prefetch next tap's B
                bn0 = *(const bfrag*)(wb + (size_t)(g + 1) * GSTR);
                bn1 = *(const bfrag*)(wb + (size_t)(g + 1) * GSTR + 512);
            }
            int ap[2];
            if constexpr (KS == 3) {
                ap[0] = apos[g][0]; ap[1] = apos[g][1];
            } else {
                const int dy = g / KS - PAD, dx = g % KS - PAD;
#pragma unroll
                for (int mt = 0; mt < 2; ++mt) {
                    const int iy = pym[mt] + dy, ix = pxm[mt] + dx;
                    const bool ok = ((unsigned)iy < (unsigned)HIN) &
                                    ((unsigned)ix < (unsigned)HIN);
                    const int pos = ok ? iy * HIN + ix : IPOS;
                    ap[mt] = pos * 64 + ((hi ^ ((pos >> 1) & 3)) << 4);
                }
            }
#pragma unroll
            for (int kh = 0; kh < 2; ++kh) {
                const bfrag bb = kh ? bc1 : bc0;
#pragma unroll
                for (int mt = 0; mt < 2; ++mt) {
                    const bfrag a = *(const bfrag*)((const char*)in_s + (ap[mt] ^ (kh << 5)));
                    acc[mt] = __builtin_amdgcn_mfma_f32_32x32x16_bf16(a, bb, acc[mt], 0, 0, 0);
                }
            }
            bc0 = bn0; bc1 = bn1;
        }
    }

    __syncthreads();
    // acc -> c_s[m][oc]: D col = lane&31, row = (r&3)+8*(r>>2)+4*(lane>>5)
#pragma unroll
    for (int mt = 0; mt < 2; ++mt)
#pragma unroll
        for (int r = 0; r < 16; ++r) {
            const int row = wvM * 64 + mt * 32 + (r & 3) + 8 * (r >> 2) + 4 * hi;
            c_s[row * 66 + wvN * 32 + lr32] = acc[mt][r];
        }
    __syncthreads();

    const int oc = tid >> 2;
    const float bv = bias[oc0 + oc];
    if (MODE == 0) {            // relu store, 2 images, 32 px per thread
        const int q = tid & 3, img = q >> 1, pl0 = (q & 1) * 32;
        __align__(16) unsigned short buf[32];
#pragma unroll
        for (int i = 0; i < 32; ++i)
            buf[i] = f2bf(fmaxf(c_s[(img * 64 + pl0 + i) * 66 + oc] + bv, 0.f));
        unsigned short* dst = out + ((size_t)((nl0 + img) * COUT + oc0 + oc)) * 64 + pl0;
        *(uint4*)(dst)      = *(uint4*)(buf);
        *(uint4*)(dst + 8)  = *(uint4*)(buf + 8);
        *(uint4*)(dst + 16) = *(uint4*)(buf + 16);
        *(uint4*)(dst + 24) = *(uint4*)(buf + 24);
    } else if (MODE == 1) {     // conv2: 2x2 pool of 8-row band (HIN=16)
        const int o0 = (tid & 3) * 8;
        __align__(16) unsigned short buf[8];
#pragma unroll
        for (int i = 0; i < 8; ++i) {
            int op = o0 + i, oy = op >> 3, ox = op & 7;
            int p = (oy * 2) * 16 + ox * 2;
            float v = fmaxf(fmaxf(c_s[p * 66 + oc],        c_s[(p + 1) * 66 + oc]),
                            fmaxf(c_s[(p + 16) * 66 + oc], c_s[(p + 17) * 66 + oc]));
            buf[i] = f2bf(fmaxf(v + bv, 0.f));
        }
        unsigned short* dst = out + ((size_t)(nl0 * COUT + oc0 + oc)) * 64
                            + (row0 >> 1) * 8 + o0;
        *(uint4*)dst = *(uint4*)buf;
    } else {                    // MODE 2: conv5 -> T5, 2 images
        const int q = tid & 3, img = q >> 1, o0 = (q & 1) * 8;
        __align__(16) unsigned short buf[8];
#pragma unroll
        for (int i = 0; i < 8; ++i) {
            int op = o0 + i, oy = op >> 2, ox = op & 3;
            int p = img * 64 + (oy * 2) * 8 + ox * 2;
            float v = fmaxf(fmaxf(c_s[p * 66 + oc],       c_s[(p + 1) * 66 + oc]),
                            fmaxf(c_s[(p + 8) * 66 + oc], c_s[(p + 9) * 66 + oc]));
            buf[i] = f2bf(fmaxf(v + bv, 0.f));
        }
        *(uint4*)(out + (size_t)(nl0 + img) * 4096 + (oc0 + oc) * 16 + o0) = *(uint4*)buf;
    }
}

// ---------------------------------------------------------------------------
// FC MFMA, split-K x4, DIRECT-FROM-GLOBAL fragments (no LDS staging, no
// in-loop barriers).  Grid (N/64, 4); block 1024 thr = 16 waves.
// Group g = tid>>8 streams k-quarter [g*K/4,(g+1)*K/4) independently:
//   A: X[m0+mt*16+(lane&15)][k0+(lane>>4)*8 ..+7]  (one uint4/lane, bf16)
//   B: W[n0+wg*16+(lane&15)][k0+(lane>>4)*8 ..+7]  (two float4/lane -> f2bf)
// (identical fragment mapping to the LDS version; X is L2-resident, intra-
// group A redundancy hits L1.)  Register double-buffer one k-step ahead.
// Final cross-group reduction through 64KB LDS (unchanged).
// ---------------------------------------------------------------------------
template<bool RELU, bool F32OUT>
__global__ __launch_bounds__(1024) void fc_mfma4(
    const unsigned short* __restrict__ X, const float* __restrict__ W,
    const float* __restrict__ Bs, void* __restrict__ Yv, int N, int K)
{
    __shared__ __align__(16) float red[4 * 64 * 64];   // 64KB

    const int tid  = threadIdx.x;
    const int lane = tid & 63;
    const int w16  = tid >> 6;                 // 0..15
    const int grp  = w16 >> 2;                 // k-quarter
    const int wg   = w16 & 3;                  // n-slice within group
    const int quad = lane >> 4, lr = lane & 15;
    const int m0 = blockIdx.y * 64, n0 = blockIdx.x * 64;
    const int KQ = K >> 2;

    accf acc[4];
#pragma unroll
    for (int i = 0; i < 4; ++i) acc[i] = (accf){0.f, 0.f, 0.f, 0.f};

    int nr = n0 + wg * 16 + lr; if (nr > N - 1) nr = N - 1;
    const unsigned short* xp = X + (size_t)(m0 + lr) * K + grp * KQ + quad * 8;
    const float*          wp = W + (size_t)nr * K + grp * KQ + quad * 8;
    const size_t mstep = (size_t)16 * K;

    uint4  xa0 = *(const uint4*)(xp);
    uint4  xa1 = *(const uint4*)(xp + mstep);
    uint4  xa2 = *(const uint4*)(xp + 2 * mstep);
    uint4  xa3 = *(const uint4*)(xp + 3 * mstep);
    float4 wa  = *(const float4*)(wp);
    float4 wb  = *(const float4*)(wp + 4);

    for (int k0 = 0; k0 < KQ; k0 += 32) {
        uint4 xn0, xn1, xn2, xn3; float4 wn, wm;
        if (k0 + 32 < KQ) {                    // prefetch next k-step
            xn0 = *(const uint4*)(xp + k0 + 32);
            xn1 = *(const uint4*)(xp + k0 + 32 + mstep);
            xn2 = *(const uint4*)(xp + k0 + 32 + 2 * mstep);
            xn3 = *(const uint4*)(xp + k0 + 32 + 3 * mstep);
            wn  = *(const float4*)(wp + k0 + 32);
            wm  = *(const float4*)(wp + k0 + 36);
        }
        __align__(16) unsigned short wb16[8] = {
            f2bf(wa.x), f2bf(wa.y), f2bf(wa.z), f2bf(wa.w),
            f2bf(wb.x), f2bf(wb.y), f2bf(wb.z), f2bf(wb.w) };
        const bfrag b = *(const bfrag*)wb16;
        acc[0] = __builtin_amdgcn_mfma_f32_16x16x32_bf16(*(const bfrag*)&xa0, b, acc[0], 0, 0, 0);
        acc[1] = __builtin_amdgcn_mfma_f32_16x16x32_bf16(*(const bfrag*)&xa1, b, acc[1], 0, 0, 0);
        acc[2] = __builtin_amdgcn_mfma_f32_16x16x32_bf16(*(const bfrag*)&xa2, b, acc[2], 0, 0, 0);
        acc[3] = __builtin_amdgcn_mfma_f32_16x16x32_bf16(*(const bfrag*)&xa3, b, acc[3], 0, 0, 0);
        if (k0 + 32 < KQ) {
            xa0 = xn0; xa1 = xn1; xa2 = xn2; xa3 = xn3;
            wa = wn; wb = wm;
        }
    }

    __syncthreads();
    // partials -> red[grp][m][n]  (row = D m = quad*4+reg, col = D n = wg*16+lr)
#pragma unroll
    for (int mt = 0; mt < 4; ++mt)
#pragma unroll
        for (int r = 0; r < 4; ++r)
            red[grp * 4096 + (mt * 16 + quad * 4 + r) * 64 + wg * 16 + lr] = acc[mt][r];
    __syncthreads();

    {   // reduce 4 partials; each thread owns 4 consecutive n of one m row
        const int m  = tid >> 4;                   // 0..63
        const int nq = (tid & 15) * 4;             // 0..60
        float4 v0 = *(const float4*)&red[            m * 64 + nq];
        float4 v1 = *(const float4*)&red[ 4096 +     m * 64 + nq];
        float4 v2 = *(const float4*)&red[ 8192 +     m * 64 + nq];
        float4 v3 = *(const float4*)&red[12288 +     m * 64 + nq];
        float s[4] = { v0.x + v1.x + v2.x + v3.x,
                       v0.y + v1.y + v2.y + v3.y,
                       v0.z + v1.z + v2.z + v3.z,
                       v0.w + v1.w + v2.w + v3.w };
#pragma unroll
        for (int i = 0; i < 4; ++i) {
            const int n = n0 + nq + i;
            if (n < N) {
                float v = s[i] + Bs[n];
                if (RELU) v = fmaxf(v, 0.f);
                if (F32OUT) ((float*)Yv)[(size_t)(m0 + m) * N + n] = v;
                else ((unsigned short*)Yv)[(size_t)(m0 + m) * N + n] = f2bf(v);
            }
        }
    }
}

// Fallback if ws too small: finite zeros.
__global__ void zero_out(float* __restrict__ out, int total)
{
    int i = blockIdx.x * 256 + threadIdx.x;
    if (i < total) out[i] = 0.f;
}

// ---------------------------------------------------------------------------
extern "C" void kernel_launch(void* const* d_in, const int* in_sizes, int n_in,
                              void* d_out, int out_size, void* d_ws, size_t ws_size,
                              hipStream_t stream)
{
    (void)in_sizes; (void)n_in;
    const float* x   = (const float*)d_in[0];
    const float* w1  = (const float*)d_in[1];
    const float* b1  = (const float*)d_in[2];
    const float* w2  = (const float*)d_in[3];
    const float* b2  = (const float*)d_in[4];
    const float* w3  = (const float*)d_in[5];
    const float* b3  = (const float*)d_in[6];
    const float* w4  = (const float*)d_in[7];
    const float* b4  = (const float*)d_in[8];
    const float* w5  = (const float*)d_in[9];
    const float* b5  = (const float*)d_in[10];
    const float* fw1 = (const float*)d_in[11];
    const float* fb1 = (const float*)d_in[12];
    const float* fw2 = (const float*)d_in[13];
    const float* fb2 = (const float*)d_in[14];
    const float* fw3 = (const float*)d_in[15];
    const float* fb3 = (const float*)d_in[16];
    float* out = (float*)d_out;

    // ws layout: WT (fragment-layout conv weights, 4,890,624 B) then CA/CB/T5.
    // Tier needs unchanged (proven ws >= 27,959,296: r5/r8 ran CH=256).
    const size_t WTB = 4890624u;
    int maxCH;
    if      (ws_size >= 27959296u) maxCH = 256;
    else if (ws_size >= 17473536u) maxCH = 128;
    else if (ws_size >= 14852096u) maxCH = 96;
    else if (ws_size >= 12230656u) maxCH = 64;
    else {
        zero_out<<<DIV_UP(out_size, 256), 256, 0, stream>>>(out, out_size);
        return;
    }
    unsigned short* wt2 = (unsigned short*)d_ws;
    unsigned short* wt3 = wt2 + 307200;
    unsigned short* wt4 = wt3 + 663552;
    unsigned short* wt5 = wt4 + 884736;
    const size_t CAb = ((size_t)maxCH * 49152u > 2097152u) ? (size_t)maxCH * 49152u : 2097152u;
    const size_t CBb = ((size_t)maxCH * 32768u > 2097152u) ? (size_t)maxCH * 32768u : 2097152u;
    unsigned short* CA = (unsigned short*)((char*)d_ws + WTB);
    unsigned short* CB = (unsigned short*)((char*)d_ws + WTB + CAb);
    unsigned short* T5 = (unsigned short*)((char*)d_ws + WTB + CAb + CBb);

    // weight pre-transforms (once per launch) into B-fragment layout
    wt_transform<<<DIV_UP(307200, 256), 256, 0, stream>>>(w2, wt2, 192, 64, 25, 307200);
    wt_transform<<<DIV_UP(663552, 256), 256, 0, stream>>>(w3, wt3, 384, 192, 9, 663552);
    wt_transform<<<DIV_UP(884736, 256), 256, 0, stream>>>(w4, wt4, 256, 384, 9, 884736);
    wt_transform<<<DIV_UP(589824, 256), 256, 0, stream>>>(w5, wt5, 256, 256, 9, 589824);

    for (int n0 = 0; n0 < 256; ) {
        const int CH = (256 - n0 < maxCH) ? (256 - n0) : maxCH;
        // conv1+pool via MFMA im2col: x -> CA [CH,64,16,16] bf16
        conv1_mfma<<<dim3(8, CH), 256, 0, stream>>>(x, w1, b1, CA, n0);
        // conv2+pool (5x5, 16x16, 2 row-bands): CA -> CB [CH,192,8,8]
        conv_mfma32<64, 5, 16, 1, 1, 192><<<dim3(6, CH), 256, 0, stream>>>(CA, wt2, b2, CB);
        // conv3 (2 images/block): CB -> CA [CH,384,8,8]
        conv_mfma32<192, 3, 8, 2, 0, 384><<<dim3(6, CH / 2), 256, 0, stream>>>(CB, wt3, b3, CA);
        // conv4: CA -> CB [CH,256,8,8]
        conv_mfma32<384, 3, 8, 2, 0, 256><<<dim3(4, CH / 2), 256, 0, stream>>>(CA, wt4, b4, CB);
        // conv5+pool: CB -> T5 rows [n0, n0+CH)
        conv_mfma32<256, 3, 8, 2, 2, 256><<<dim3(4, CH / 2), 256, 0, stream>>>(
            CB, wt5, b5, T5 + (size_t)n0 * 4096);
        n0 += CH;
    }

    // fc1 + relu: T5[256,4096] -> CA (bf16 [256,4096])
    fc_mfma4<true, false><<<dim3(64, 4), 1024, 0, stream>>>(T5, fw1, fb1, CA, 4096, 4096);
    // fc2 + relu: CA -> CB
    fc_mfma4<true, false><<<dim3(64, 4), 1024, 0, stream>>>(CA, fw2, fb2, CB, 4096, 4096);
    // fc3: CB -> out f32 [256,1000]
    fc_mfma4<false, true><<<dim3(16, 4), 1024, 0, stream>>>(CB, fw3, fb3, out, 1000, 4096);
}

// Round 11
// 436.104 us; speedup vs baseline: 1.3545x; 1.3545x over previous
//
#include <hip/hip_runtime.h>
#include <hip/hip_bf16.h>

#define DIV_UP(a,b) (((a)+(b)-1)/(b))

typedef __attribute__((ext_vector_type(8))) short bfrag;    // 8 bf16 = 4 VGPR
typedef __attribute__((ext_vector_type(4))) float accf;     // 16x16 MFMA acc
typedef __attribute__((ext_vector_type(16))) float accf16;  // 32x32 MFMA acc

__device__ __forceinline__ unsigned short f2bf(float f) {
    __hip_bfloat16 h = __float2bfloat16(f);
    return *reinterpret_cast<unsigned short*>(&h);
}

// ---------------------------------------------------------------------------
// conv1 + pool1 via MFMA im2col: x[256,3,32,32] f32 -> CA[chunk,64,16,16] bf16.
// ---------------------------------------------------------------------------
__global__ __launch_bounds__(256) void conv1_mfma(
    const float* __restrict__ in, const float* __restrict__ w,
    const float* __restrict__ bias, unsigned short* __restrict__ out, int n0)
{
    constexpr int RAWS = 3 * 6 * 34;            // 612 shorts ([3][6][34] bf16)
    constexpr int INS  = 128 * 32;              // im2col [128 pos][32 k]
    constexpr int WSZ  = 64 * 32;               // [64 oc][32 k]
    constexpr int CS   = 128 * 66;              // floats
    constexpr int SMEM = (CS * 4 > (RAWS + 4 + INS + WSZ) * 2)
                       ? CS * 4 : (RAWS + 4 + INS + WSZ) * 2;
    __shared__ __align__(16) char smem[SMEM];
    short* raw_s = (short*)smem;
    short* in_s  = raw_s + RAWS + 4;
    short* w_s   = in_s + INS;
    float* c_s   = (float*)smem;

    const int tid  = threadIdx.x;
    const int lane = tid & 63, wv = tid >> 6;
    const int quad = lane >> 4, lr = lane & 15;
    const int rb   = blockIdx.x;
    const int nl   = blockIdx.y;
    const int n    = n0 + nl;
    const int row0 = rb * 4;

    for (int idx = tid; idx < RAWS; idx += 256) {
        int c = idx / 204, rem = idx - c * 204;
        int ry = rem / 34, rx = rem - ry * 34;
        int iy = row0 - 1 + ry, ix = rx - 1;
        float v = 0.f;
        if (iy >= 0 && iy < 32 && ix >= 0 && ix < 32)
            v = in[((n * 3 + c) * 32 + iy) * 32 + ix];
        raw_s[idx] = (short)f2bf(v);
    }
    {
        const int soc = tid >> 2, cbq = tid & 3;
        const int wsw = ((cbq ^ ((soc >> 1) & 3)) << 3);
        __align__(16) unsigned short buf[8];
#pragma unroll
        for (int j = 0; j < 8; ++j) {
            int k = cbq * 8 + j;
            buf[j] = (k < 27) ? f2bf(w[soc * 27 + k]) : (unsigned short)0;
        }
        *(uint4*)&w_s[soc * 32 + wsw] = *(uint4*)buf;
    }
    __syncthreads();
    {
        const int k = tid & 31, pg = tid >> 5;
        const int shi = k >> 3, slo = k & 7;
        const bool valid = (k < 27);
        int cbase = 0;
        if (valid) {
            int c = k / 9, rr = k - c * 9;
            int ky = rr / 3, kx = rr - ky * 3;
            cbase = c * 204 + ky * 34 + kx;
        }
        const int prow = pg >> 1, pcol0 = (pg & 1) * 16;
        const int rbase = cbase + prow * 34 + pcol0;
#pragma unroll
        for (int i = 0; i < 16; ++i) {
            const int pos = prow * 32 + pcol0 + i;
            short v = valid ? raw_s[rbase + i] : (short)0;
            in_s[pos * 32 + ((shi ^ ((pos >> 1) & 3)) << 3) + slo] = v;
        }
    }
    __syncthreads();
    const int bswz = (quad ^ ((lr >> 1) & 3)) << 3;
    const bfrag b = *(const bfrag*)(w_s + (wv * 16 + lr) * 32 + bswz);
    accf acc[8];
#pragma unroll
    for (int mt = 0; mt < 8; ++mt) {
        const int pos = mt * 16 + lr;
        const bfrag a = *(const bfrag*)(in_s + pos * 32 + ((quad ^ ((pos >> 1) & 3)) << 3));
        acc[mt] = __builtin_amdgcn_mfma_f32_16x16x32_bf16(
            a, b, (accf){0.f, 0.f, 0.f, 0.f}, 0, 0, 0);
    }
    __syncthreads();
#pragma unroll
    for (int mt = 0; mt < 8; ++mt)
#pragma unroll
        for (int r = 0; r < 4; ++r)
            c_s[(mt * 16 + quad * 4 + r) * 66 + wv * 16 + lr] = acc[mt][r];
    __syncthreads();
    {
        const int oc = tid >> 2;
        const float bv = bias[oc];
        const int o0 = (tid & 3) * 8;
        __align__(16) unsigned short buf[8];
#pragma unroll
        for (int i = 0; i < 8; ++i) {
            int op = o0 + i, oy = op >> 4, ox = op & 15;
            int p = (oy * 2) * 32 + ox * 2;
            float v = fmaxf(fmaxf(c_s[p * 66 + oc],        c_s[(p + 1) * 66 + oc]),
                            fmaxf(c_s[(p + 32) * 66 + oc], c_s[(p + 33) * 66 + oc]));
            buf[i] = f2bf(fmaxf(v + bv, 0.f));
        }
        unsigned short* dst = out + ((size_t)(nl * 64 + oc)) * 256 + (row0 >> 1) * 16 + o0;
        *(uint4*)dst = *(uint4*)buf;
    }
}

// ---------------------------------------------------------------------------
// Weight pre-transform (once per launch): f32 OIHW -> bf16, fragment layout
// for conv_mfma32 (see r7 comment).
// ---------------------------------------------------------------------------
__global__ __launch_bounds__(256) void wt_transform(
    const float* __restrict__ w, unsigned short* __restrict__ wt,
    int COUT, int CIN, int KK, int total)
{
    int idx = blockIdx.x * 256 + threadIdx.x;
    if (idx >= total) return;
    const int j    = idx & 7;
    const int lane = (idx >> 3) & 63;
    const int kh   = (idx >> 9) & 1;
    int t = idx >> 10;
    const int NOCG = COUT >> 5;
    const int ocg  = t % NOCG; t /= NOCG;
    const int NC   = CIN >> 5;
    const int cc   = t % NC;
    const int g    = t / NC;
    const int oc = ocg * 32 + (lane & 31);
    const int ci = cc * 32 + kh * 16 + (lane >> 5) * 8 + j;
    wt[idx] = f2bf(w[((size_t)oc * CIN + ci) * KK + g]);
}

// ---------------------------------------------------------------------------
// 32x32x16-MFMA implicit-GEMM conv (unchanged from r8, verified).
// ---------------------------------------------------------------------------
template<int CIN, int KS, int HIN, int IMGS, int MODE, int COUT>
__global__ __launch_bounds__(256) void conv_mfma32(
    const unsigned short* __restrict__ in, const unsigned short* __restrict__ wt,
    const float* __restrict__ bias, unsigned short* __restrict__ out)
{
    constexpr int PAD  = KS / 2;
    constexpr int KK   = KS * KS;
    constexpr int PIX  = HIN * HIN;
    constexpr int NC   = CIN / 32;
    constexpr int NOCG = COUT / 32;
    constexpr int IPOS = IMGS * PIX;               // staged positions
    constexpr int ROWB = (IMGS == 1) ? PIX / 128 : 1;
    constexpr int INS  = IPOS * 32 + 32;           // shorts (incl zero row)
    constexpr int CS   = 128 * 66;                 // floats
    constexpr int SMEM = (INS * 2 > CS * 4) ? INS * 2 : CS * 4;
    constexpr int GSTR = NC * NOCG * 1024;         // wt shorts per tap g

    __shared__ __align__(16) char smem[SMEM];
    short* in_s = (short*)smem;
    float* c_s  = (float*)smem;

    const int tid  = threadIdx.x;
    const int lane = tid & 63, wv = tid >> 6;
    const int hi   = lane >> 5, lr32 = lane & 31;
    const int wvM  = wv >> 1, wvN = wv & 1;
    const int ocb  = blockIdx.x / ROWB, rb = blockIdx.x % ROWB;
    const int oc0  = ocb * 64;
    const int nl0  = (IMGS == 2) ? blockIdx.y * 2 : blockIdx.y;
    const int row0 = rb * (128 / HIN);             // conv2 band start row

    if (tid < 32) in_s[IPOS * 32 + tid] = 0;       // zero row for OOB taps

    accf16 acc[2];
#pragma unroll
    for (int i = 0; i < 2; ++i)
#pragma unroll
        for (int r = 0; r < 16; ++r) acc[i][r] = 0.f;

    // Hoisted A addressing (KS==3); conv2 computes inline.
    int pym[2], pxm[2];
#pragma unroll
    for (int mt = 0; mt < 2; ++mt) {
        const int m = wvM * 64 + mt * 32 + lr32;
        pym[mt] = row0 + m / HIN;
        pxm[mt] = m % HIN;
    }
    int apos[KK][2];
    if constexpr (KS == 3) {
#pragma unroll
        for (int g = 0; g < KK; ++g) {
            const int dy = g / 3 - 1, dx = g % 3 - 1;
#pragma unroll
            for (int mt = 0; mt < 2; ++mt) {
                const int m = wvM * 64 + mt * 32 + lr32;
                const int img = m >> 6, p = m & 63;
                const int iy = (p >> 3) + dy, ix = (p & 7) + dx;
                const bool ok = ((unsigned)iy < 8u) & ((unsigned)ix < 8u);
                const int pos = ok ? img * 64 + iy * 8 + ix : IPOS;
                apos[g][mt] = pos * 64 + ((hi ^ ((pos >> 1) & 3)) << 4);
            }
        }
    }

    const int sci = tid & 31, slot = tid >> 5;
    const int shi = sci >> 3, slo = sci & 7;
    // B fragment base: this wave's oc-group, lane-contiguous layout.
    const unsigned short* wbase = wt + (size_t)(oc0 / 32 + wvN) * 1024 + lane * 8;

    for (int c0 = 0; c0 < CIN; c0 += 32) {
        const unsigned short* wb = wbase + (size_t)(c0 >> 5) * (NOCG * 1024);
        __syncthreads();
        // stage input images -> in_s[pos][ci] (swizzled 16B slots)
#pragma unroll
        for (int img = 0; img < IMGS; ++img) {
            const unsigned short* src = in + ((size_t)((nl0 + img) * CIN + c0 + sci)) * PIX;
            for (int iy = slot; iy < HIN; iy += 8) {
#pragma unroll
                for (int xc = 0; xc < HIN; xc += 8) {
                    uint4 v = *(const uint4*)(src + iy * HIN + xc);
                    const int p0 = img * PIX + iy * HIN + xc;
                    unsigned short e[8];
                    e[0] = (unsigned short)(v.x & 0xFFFF); e[1] = (unsigned short)(v.x >> 16);
                    e[2] = (unsigned short)(v.y & 0xFFFF); e[3] = (unsigned short)(v.y >> 16);
                    e[4] = (unsigned short)(v.z & 0xFFFF); e[5] = (unsigned short)(v.z >> 16);
                    e[6] = (unsigned short)(v.w & 0xFFFF); e[7] = (unsigned short)(v.w >> 16);
#pragma unroll
                    for (int k = 0; k < 8; ++k) {
                        const int p = p0 + k;
                        in_s[p * 32 + ((shi ^ ((p >> 1) & 3)) << 3) + slo] = (short)e[k];
                    }
                }
            }
        }
        // issue first B loads while staging drains
        bfrag bc0 = *(const bfrag*)(wb);
        bfrag bc1 = *(const bfrag*)(wb + 512);
        __syncthreads();
#pragma unroll
        for (int g = 0; g < KK; ++g) {
            bfrag bn0 = bc0, bn1 = bc1;
            if (g + 1 < KK) {                      // prefetch next tap's B
                bn0 = *(const bfrag*)(wb + (size_t)(g + 1) * GSTR);
                bn1 = *(const bfrag*)(wb + (size_t)(g + 1) * GSTR + 512);
            }
            int ap[2];
            if constexpr (KS == 3) {
                ap[0] = apos[g][0]; ap[1] = apos[g][1];
            } else {
                const int dy = g / KS - PAD, dx = g % KS - PAD;
#pragma unroll
                for (int mt = 0; mt < 2; ++mt) {
                    const int iy = pym[mt] + dy, ix = pxm[mt] + dx;
                    const bool ok = ((unsigned)iy < (unsigned)HIN) &
                                    ((unsigned)ix < (unsigned)HIN);
                    const int pos = ok ? iy * HIN + ix : IPOS;
                    ap[mt] = pos * 64 + ((hi ^ ((pos >> 1) & 3)) << 4);
                }
            }
#pragma unroll
            for (int kh = 0; kh < 2; ++kh) {
                const bfrag bb = kh ? bc1 : bc0;
#pragma unroll
                for (int mt = 0; mt < 2; ++mt) {
                    const bfrag a = *(const bfrag*)((const char*)in_s + (ap[mt] ^ (kh << 5)));
                    acc[mt] = __builtin_amdgcn_mfma_f32_32x32x16_bf16(a, bb, acc[mt], 0, 0, 0);
                }
            }
            bc0 = bn0; bc1 = bn1;
        }
    }

    __syncthreads();
    // acc -> c_s[m][oc]: D col = lane&31, row = (r&3)+8*(r>>2)+4*(lane>>5)
#pragma unroll
    for (int mt = 0; mt < 2; ++mt)
#pragma unroll
        for (int r = 0; r < 16; ++r) {
            const int row = wvM * 64 + mt * 32 + (r & 3) + 8 * (r >> 2) + 4 * hi;
            c_s[row * 66 + wvN * 32 + lr32] = acc[mt][r];
        }
    __syncthreads();

    const int oc = tid >> 2;
    const float bv = bias[oc0 + oc];
    if (MODE == 0) {            // relu store, 2 images, 32 px per thread
        const int q = tid & 3, img = q >> 1, pl0 = (q & 1) * 32;
        __align__(16) unsigned short buf[32];
#pragma unroll
        for (int i = 0; i < 32; ++i)
            buf[i] = f2bf(fmaxf(c_s[(img * 64 + pl0 + i) * 66 + oc] + bv, 0.f));
        unsigned short* dst = out + ((size_t)((nl0 + img) * COUT + oc0 + oc)) * 64 + pl0;
        *(uint4*)(dst)      = *(uint4*)(buf);
        *(uint4*)(dst + 8)  = *(uint4*)(buf + 8);
        *(uint4*)(dst + 16) = *(uint4*)(buf + 16);
        *(uint4*)(dst + 24) = *(uint4*)(buf + 24);
    } else if (MODE == 1) {     // conv2: 2x2 pool of 8-row band (HIN=16)
        const int o0 = (tid & 3) * 8;
        __align__(16) unsigned short buf[8];
#pragma unroll
        for (int i = 0; i < 8; ++i) {
            int op = o0 + i, oy = op >> 3, ox = op & 7;
            int p = (oy * 2) * 16 + ox * 2;
            float v = fmaxf(fmaxf(c_s[p * 66 + oc],        c_s[(p + 1) * 66 + oc]),
                            fmaxf(c_s[(p + 16) * 66 + oc], c_s[(p + 17) * 66 + oc]));
            buf[i] = f2bf(fmaxf(v + bv, 0.f));
        }
        unsigned short* dst = out + ((size_t)(nl0 * COUT + oc0 + oc)) * 64
                            + (row0 >> 1) * 8 + o0;
        *(uint4*)dst = *(uint4*)buf;
    } else {                    // MODE 2: conv5 -> T5, 2 images
        const int q = tid & 3, img = q >> 1, o0 = (q & 1) * 8;
        __align__(16) unsigned short buf[8];
#pragma unroll
        for (int i = 0; i < 8; ++i) {
            int op = o0 + i, oy = op >> 2, ox = op & 3;
            int p = img * 64 + (oy * 2) * 8 + ox * 2;
            float v = fmaxf(fmaxf(c_s[p * 66 + oc],       c_s[(p + 1) * 66 + oc]),
                            fmaxf(c_s[(p + 8) * 66 + oc], c_s[(p + 9) * 66 + oc]));
            buf[i] = f2bf(fmaxf(v + bv, 0.f));
        }
        *(uint4*)(out + (size_t)(nl0 + img) * 4096 + (oc0 + oc) * 16 + o0) = *(uint4*)buf;
    }
}

// ---------------------------------------------------------------------------
// FC split-K across BLOCKS: grid (N/64, 4 m-blocks x 4 kz), 256 thr (4 waves).
// Each block = verified r5 fc body over K-quarter kz; LDS-staged coalesced
// loads; stores 64x64 f32 partial to P[(kz*256+m)*N+n].  4 independent
// blocks/CU with separate barrier domains hide the k-step load latency.
// ---------------------------------------------------------------------------
__global__ __launch_bounds__(256) void fc_sk(
    const unsigned short* __restrict__ X, const float* __restrict__ W,
    float* __restrict__ P, int N, int K)
{
    __shared__ __align__(16) short Xs[64 * 32];
    __shared__ __align__(16) short Ws[64 * 32];
    const int tid  = threadIdx.x;
    const int lane = tid & 63, wv = tid >> 6;
    const int quad = lane >> 4, lr = lane & 15;
    const int n0 = blockIdx.x * 64;
    const int m0 = (blockIdx.y >> 2) * 64;
    const int kz = blockIdx.y & 3;
    const int mm = tid >> 2, ko = (tid & 3) * 8;
    const int KQ = K >> 2;

    accf acc[4];
#pragma unroll
    for (int i = 0; i < 4; ++i) acc[i] = (accf){0.f, 0.f, 0.f, 0.f};

    int nr = n0 + mm; if (nr > N - 1) nr = N - 1;
    const unsigned short* xp = X + (size_t)(m0 + mm) * K + (size_t)kz * KQ + ko;
    const float*          wp = W + (size_t)nr * K + (size_t)kz * KQ + ko;

    const int wsw = (((tid & 3) ^ ((mm >> 1) & 3)) << 3);            // shorts
    const int rsw = ((quad ^ ((lr >> 1) & 3)) << 3);                 // shorts

    uint4  xv = *(const uint4*)(xp);
    float4 wa = *(const float4*)(wp);
    float4 wb = *(const float4*)(wp + 4);

    for (int k0 = 0; k0 < KQ; k0 += 32) {
        __syncthreads();
        *(uint4*)&Xs[mm * 32 + wsw] = xv;
        __align__(16) unsigned short wb16[8] = {
            f2bf(wa.x), f2bf(wa.y), f2bf(wa.z), f2bf(wa.w),
            f2bf(wb.x), f2bf(wb.y), f2bf(wb.z), f2bf(wb.w) };
        *(uint4*)&Ws[mm * 32 + wsw] = *(uint4*)wb16;
        __syncthreads();
        if (k0 + 32 < KQ) {                        // prefetch next k-step
            xv = *(const uint4*)(xp + k0 + 32);
            wa = *(const float4*)(wp + k0 + 32);
            wb = *(const float4*)(wp + k0 + 36);
        }
        const bfrag b = *(const bfrag*)(Ws + (wv * 16 + lr) * 32 + rsw);
#pragma unroll
        for (int mt = 0; mt < 4; ++mt) {
            const bfrag a = *(const bfrag*)(Xs + (mt * 16 + lr) * 32 + rsw);
            acc[mt] = __builtin_amdgcn_mfma_f32_16x16x32_bf16(a, b, acc[mt], 0, 0, 0);
        }
    }

    const int n = n0 + wv * 16 + lr;
    if (n < N) {
#pragma unroll
        for (int mt = 0; mt < 4; ++mt)
#pragma unroll
            for (int r = 0; r < 4; ++r) {
                const int m = m0 + mt * 16 + quad * 4 + r;
                P[((size_t)kz * 256 + m) * N + n] = acc[mt][r];
            }
    }
}

// Reduce 4 k-split partials + bias (+relu) -> bf16 or f32 output.
template<bool RELU, bool F32OUT>
__global__ __launch_bounds__(256) void fc_red(
    const float* __restrict__ P, const float* __restrict__ Bs,
    void* __restrict__ Yv, int N, int total4)
{
    int idx = blockIdx.x * 256 + threadIdx.x;
    if (idx >= total4) return;
    const int nq = N >> 2;
    const int m = idx / nq;
    const int n = (idx - m * nq) * 4;
    const float* p = P + (size_t)m * N + n;
    const size_t st = (size_t)256 * N;
    float4 v0 = *(const float4*)(p);
    float4 v1 = *(const float4*)(p + st);
    float4 v2 = *(const float4*)(p + 2 * st);
    float4 v3 = *(const float4*)(p + 3 * st);
    float4 bb = *(const float4*)(Bs + n);
    float s[4] = { v0.x + v1.x + v2.x + v3.x + bb.x,
                   v0.y + v1.y + v2.y + v3.y + bb.y,
                   v0.z + v1.z + v2.z + v3.z + bb.z,
                   v0.w + v1.w + v2.w + v3.w + bb.w };
    if (RELU) {
#pragma unroll
        for (int i = 0; i < 4; ++i) s[i] = fmaxf(s[i], 0.f);
    }
    if (F32OUT) {
        *(float4*)((float*)Yv + (size_t)m * N + n) = (float4){s[0], s[1], s[2], s[3]};
    } else {
        __align__(8) unsigned short h[4] = { f2bf(s[0]), f2bf(s[1]), f2bf(s[2]), f2bf(s[3]) };
        *(uint2*)((unsigned short*)Yv + (size_t)m * N + n) = *(uint2*)h;
    }
}

// ---------------------------------------------------------------------------
// FC MFMA, intra-block split-K x4 (r8 verified version) — fallback for small
// ws tiers where the 16MB partial buffer doesn't fit.
// ---------------------------------------------------------------------------
template<bool RELU, bool F32OUT>
__global__ __launch_bounds__(1024) void fc_mfma4(
    const unsigned short* __restrict__ X, const float* __restrict__ W,
    const float* __restrict__ Bs, void* __restrict__ Yv, int N, int K)
{
    __shared__ __align__(16) char smem[65536];
    short* stag = (short*)smem;
    float* red  = (float*)smem;

    const int tid  = threadIdx.x;
    const int lane = tid & 63;
    const int w16  = tid >> 6;
    const int grp  = w16 >> 2;
    const int wg   = w16 & 3;
    const int quad = lane >> 4, lr = lane & 15;
    const int m0 = blockIdx.y * 64, n0 = blockIdx.x * 64;
    const int gtid = tid & 255;
    const int mm = gtid >> 2, ko = (gtid & 3) * 8;
    const int KQ = K >> 2;

    short* Xs = stag + grp * 4096;
    short* Ws = Xs + 2048;

    accf acc[4];
#pragma unroll
    for (int i = 0; i < 4; ++i) acc[i] = (accf){0.f, 0.f, 0.f, 0.f};

    int nr = n0 + mm; if (nr > N - 1) nr = N - 1;
    const unsigned short* xp = X + (size_t)(m0 + mm) * K + (size_t)grp * KQ + ko;
    const float*          wp = W + (size_t)nr * K + (size_t)grp * KQ + ko;

    const int wsw = (((gtid & 3) ^ ((mm >> 1) & 3)) << 3);
    const int rsw = ((quad ^ ((lr >> 1) & 3)) << 3);

    uint4  xv = *(const uint4*)(xp);
    float4 wa = *(const float4*)(wp);
    float4 wb = *(const float4*)(wp + 4);

    for (int k0 = 0; k0 < KQ; k0 += 32) {
        __syncthreads();
        *(uint4*)&Xs[mm * 32 + wsw] = xv;
        __align__(16) unsigned short wb16[8] = {
            f2bf(wa.x), f2bf(wa.y), f2bf(wa.z), f2bf(wa.w),
            f2bf(wb.x), f2bf(wb.y), f2bf(wb.z), f2bf(wb.w) };
        *(uint4*)&Ws[mm * 32 + wsw] = *(uint4*)wb16;
        __syncthreads();
        if (k0 + 32 < KQ) {
            xv = *(const uint4*)(xp + k0 + 32);
            wa = *(const float4*)(wp + k0 + 32);
            wb = *(const float4*)(wp + k0 + 36);
        }
        const bfrag b = *(const bfrag*)(Ws + (wg * 16 + lr) * 32 + rsw);
#pragma unroll
        for (int mt = 0; mt < 4; ++mt) {
            const bfrag a = *(const bfrag*)(Xs + (mt * 16 + lr) * 32 + rsw);
            acc[mt] = __builtin_amdgcn_mfma_f32_16x16x32_bf16(a, b, acc[mt], 0, 0, 0);
        }
    }

    __syncthreads();
#pragma unroll
    for (int mt = 0; mt < 4; ++mt)
#pragma unroll
        for (int r = 0; r < 4; ++r)
            red[grp * 4096 + (mt * 16 + quad * 4 + r) * 64 + wg * 16 + lr] = acc[mt][r];
    __syncthreads();

    {
        const int m  = tid >> 4;
        const int nq = (tid & 15) * 4;
        float4 v0 = *(const float4*)&red[            m * 64 + nq];
        float4 v1 = *(const float4*)&red[ 4096 +     m * 64 + nq];
        float4 v2 = *(const float4*)&red[ 8192 +     m * 64 + nq];
        float4 v3 = *(const float4*)&red[12288 +     m * 64 + nq];
        float s[4] = { v0.x + v1.x + v2.x + v3.x,
                       v0.y + v1.y + v2.y + v3.y,
                       v0.z + v1.z + v2.z + v3.z,
                       v0.w + v1.w + v2.w + v3.w };
#pragma unroll
        for (int i = 0; i < 4; ++i) {
            const int n = n0 + nq + i;
            if (n < N) {
                float v = s[i] + Bs[n];
                if (RELU) v = fmaxf(v, 0.f);
                if (F32OUT) ((float*)Yv)[(size_t)(m0 + m) * N + n] = v;
                else ((unsigned short*)Yv)[(size_t)(m0 + m) * N + n] = f2bf(v);
            }
        }
    }
}

// Fallback if ws too small: finite zeros.
__global__ void zero_out(float* __restrict__ out, int total)
{
    int i = blockIdx.x * 256 + threadIdx.x;
    if (i < total) out[i] = 0.f;
}

// ---------------------------------------------------------------------------
extern "C" void kernel_launch(void* const* d_in, const int* in_sizes, int n_in,
                              void* d_out, int out_size, void* d_ws, size_t ws_size,
                              hipStream_t stream)
{
    (void)in_sizes; (void)n_in;
    const float* x   = (const float*)d_in[0];
    const float* w1  = (const float*)d_in[1];
    const float* b1  = (const float*)d_in[2];
    const float* w2  = (const float*)d_in[3];
    const float* b2  = (const float*)d_in[4];
    const float* w3  = (const float*)d_in[5];
    const float* b3  = (const float*)d_in[6];
    const float* w4  = (const float*)d_in[7];
    const float* b4  = (const float*)d_in[8];
    const float* w5  = (const float*)d_in[9];
    const float* b5  = (const float*)d_in[10];
    const float* fw1 = (const float*)d_in[11];
    const float* fb1 = (const float*)d_in[12];
    const float* fw2 = (const float*)d_in[13];
    const float* fb2 = (const float*)d_in[14];
    const float* fw3 = (const float*)d_in[15];
    const float* fb3 = (const float*)d_in[16];
    float* out = (float*)d_out;

    // ws layout (conv phase): WT 0..4.89MB, CA, CB, T5 (as r8).
    // FC phase (tier 256 only): WT dead ->
    //   F1 (fc1 out bf16 2MB) @0; F2 (fc2 out) @2MB;
    //   P  (split-K f32 partials, 16MB) @4MB  (ends 20.97MB < T5 @25.86MB).
    const size_t WTB = 4890624u;
    int maxCH;
    if      (ws_size >= 27959296u) maxCH = 256;
    else if (ws_size >= 17473536u) maxCH = 128;
    else if (ws_size >= 14852096u) maxCH = 96;
    else if (ws_size >= 12230656u) maxCH = 64;
    else {
        zero_out<<<DIV_UP(out_size, 256), 256, 0, stream>>>(out, out_size);
        return;
    }
    unsigned short* wt2 = (unsigned short*)d_ws;
    unsigned short* wt3 = wt2 + 307200;
    unsigned short* wt4 = wt3 + 663552;
    unsigned short* wt5 = wt4 + 884736;
    const size_t CAb = ((size_t)maxCH * 49152u > 2097152u) ? (size_t)maxCH * 49152u : 2097152u;
    const size_t CBb = ((size_t)maxCH * 32768u > 2097152u) ? (size_t)maxCH * 32768u : 2097152u;
    unsigned short* CA = (unsigned short*)((char*)d_ws + WTB);
    unsigned short* CB = (unsigned short*)((char*)d_ws + WTB + CAb);
    unsigned short* T5 = (unsigned short*)((char*)d_ws + WTB + CAb + CBb);

    // weight pre-transforms (once per launch) into B-fragment layout
    wt_transform<<<DIV_UP(307200, 256), 256, 0, stream>>>(w2, wt2, 192, 64, 25, 307200);
    wt_transform<<<DIV_UP(663552, 256), 256, 0, stream>>>(w3, wt3, 384, 192, 9, 663552);
    wt_transform<<<DIV_UP(884736, 256), 256, 0, stream>>>(w4, wt4, 256, 384, 9, 884736);
    wt_transform<<<DIV_UP(589824, 256), 256, 0, stream>>>(w5, wt5, 256, 256, 9, 589824);

    for (int n0 = 0; n0 < 256; ) {
        const int CH = (256 - n0 < maxCH) ? (256 - n0) : maxCH;
        conv1_mfma<<<dim3(8, CH), 256, 0, stream>>>(x, w1, b1, CA, n0);
        conv_mfma32<64, 5, 16, 1, 1, 192><<<dim3(6, CH), 256, 0, stream>>>(CA, wt2, b2, CB);
        conv_mfma32<192, 3, 8, 2, 0, 384><<<dim3(6, CH / 2), 256, 0, stream>>>(CB, wt3, b3, CA);
        conv_mfma32<384, 3, 8, 2, 0, 256><<<dim3(4, CH / 2), 256, 0, stream>>>(CA, wt4, b4, CB);
        conv_mfma32<256, 3, 8, 2, 2, 256><<<dim3(4, CH / 2), 256, 0, stream>>>(
            CB, wt5, b5, T5 + (size_t)n0 * 4096);
        n0 += CH;
    }

    if (maxCH == 256) {
        // block-level split-K x4 with workspace partials (WT region now dead)
        unsigned short* F1 = (unsigned short*)d_ws;
        unsigned short* F2 = F1 + 1048576;
        float* P = (float*)((char*)d_ws + 4194304);
        // fc1 + relu: T5[256,4096] -> F1 (bf16)
        fc_sk<<<dim3(64, 16), 256, 0, stream>>>(T5, fw1, P, 4096, 4096);
        fc_red<true, false><<<DIV_UP(262144, 256), 256, 0, stream>>>(P, fb1, F1, 4096, 262144);
        // fc2 + relu: F1 -> F2 (bf16)
        fc_sk<<<dim3(64, 16), 256, 0, stream>>>(F1, fw2, P, 4096, 4096);
        fc_red<true, false><<<DIV_UP(262144, 256), 256, 0, stream>>>(P, fb2, F2, 4096, 262144);
        // fc3: F2 -> out f32 [256,1000]
        fc_sk<<<dim3(16, 16), 256, 0, stream>>>(F2, fw3, P, 1000, 4096);
        fc_red<false, true><<<DIV_UP(64000, 256), 256, 0, stream>>>(P, fb3, out, 1000, 64000);
    } else {
        // small-ws fallback: r8 in-block split-K (CA/CB reused as before)
        fc_mfma4<true, false><<<dim3(64, 4), 1024, 0, stream>>>(T5, fw1, fb1, CA, 4096, 4096);
        fc_mfma4<true, false><<<dim3(64, 4), 1024, 0, stream>>>(CA, fw2, fb2, CB, 4096, 4096);
        fc_mfma4<false, true><<<dim3(16, 4), 1024, 0, stream>>>(CB, fw3, fb3, out, 1000, 4096);
    }
}